// Round 7
// baseline (1911.285 us; speedup 1.0000x reference)
//
#include <hip/hip_runtime.h>
#include <hip/hip_bf16.h>

#define NN 10000
#define NE 320000
#define HD 128
#define TILE 128
#define NTILES (NE / TILE)   // 2500 exactly

typedef __attribute__((ext_vector_type(8))) short s16x8;
typedef __attribute__((ext_vector_type(4))) short s16x4;
typedef __attribute__((ext_vector_type(4))) float f32x4;

__device__ __forceinline__ short f2bf(float f) {
    union { float f; unsigned u; } v; v.f = f;
    unsigned r = v.u + 0x7FFFu + ((v.u >> 16) & 1u);   // RNE
    return (short)(r >> 16);
}
__device__ __forceinline__ float bf2f(short s) {
    union { unsigned u; float f; } v;
    v.u = ((unsigned)(unsigned short)s) << 16;
    return v.f;
}

// ---------------- CSR build (edges sorted by dst) + fused weight prep ----------------
struct WPtrs { const float* w[8]; };

__global__ void hist_kernel(const int* __restrict__ dst, int* __restrict__ cnt,
                            WPtrs p, ushort* __restrict__ wdst) {
    int e = blockIdx.x * blockDim.x + threadIdx.x;
    if (e < NE) atomicAdd(&cnt[dst[e]], 1);
    int tid = e;
    int m, idx;
    if (tid < 7 * 16384) { m = tid >> 14; idx = tid & 16383; }
    else if (tid < 7 * 16384 + 2048) { m = 7; idx = tid - 7 * 16384; }
    else return;
    int b = m >> 1, l = m & 1;
    int C = (m == 7) ? 16 : 128;
    int k = idx / C, c = idx % C;
    float v = p.w[m][k * C + c];
    wdst[l * 65536 + b * 16384 + c * 128 + k] = (ushort)f2bf(v);
}

__global__ void scan_kernel(const int* __restrict__ cnt, int* __restrict__ rs, int* __restrict__ cur) {
    __shared__ int part[256];
    int t = threadIdx.x;
    const int CH = (NN + 255) / 256;  // 40
    int base = t * CH;
    int s = 0;
    for (int i = 0; i < CH; i++) {
        int idx = base + i;
        if (idx < NN) s += cnt[idx];
    }
    part[t] = s;
    __syncthreads();
    for (int off = 1; off < 256; off <<= 1) {
        int v = (t >= off) ? part[t - off] : 0;
        __syncthreads();
        part[t] += v;
        __syncthreads();
    }
    int run = part[t] - s;
    for (int i = 0; i < CH; i++) {
        int idx = base + i;
        if (idx < NN) {
            rs[idx] = run;
            cur[idx] = run;
            run += cnt[idx];
        }
    }
    if (t == 255) rs[NN] = run;
}

__global__ void scatter_kernel(const int* __restrict__ src, const int* __restrict__ dst,
                               int* __restrict__ cur, int* __restrict__ ssrc) {
    int e = blockIdx.x * blockDim.x + threadIdx.x;
    if (e < NE) {
        int p = atomicAdd(&cur[dst[e]], 1);
        ssrc[p] = src[e];
    }
}

__global__ void nodeof_kernel(const int* __restrict__ rs, int* __restrict__ nof) {
    int n = blockIdx.x * blockDim.x + threadIdx.x;
    if (n < NN) {
        int b = rs[n], e = rs[n + 1];
        for (int s = b; s < e; s++) nof[s] = n;
    }
}

// ---------------- per-node layer-1 factorization -> bf16 A/B, fused zero-fill ----------------
template<int D, int ZD>
__global__ __launch_bounds__(256)
void nodeAB_kernel(const float* __restrict__ x, const float* __restrict__ W0,
                   const float* __restrict__ b0, ushort* __restrict__ A,
                   ushort* __restrict__ Bm, float* __restrict__ zbuf) {
    __shared__ float xs[8 * 128];
    int t = threadIdx.x;
    int n0 = blockIdx.x * 8;
    for (int i = t; i < 8 * D; i += 256) {
        int n = i / D, d = i % D;
        xs[n * 128 + d] = x[(size_t)(n0 + n) * D + d];
    }
    for (int i = t; i < 8 * ZD; i += 256) zbuf[(size_t)n0 * ZD + i] = 0.f;
    __syncthreads();
    int c = t & 127;
    int h = t >> 7;
    float a[4], b[4];
    float bias = b0[c];
#pragma unroll
    for (int n = 0; n < 4; n++) { a[n] = bias; b[n] = 0.f; }
    for (int d = 0; d < D; d++) {
        float wt = W0[d * HD + c];
        float wb = W0[(D + d) * HD + c];
        float wd = wt - wb;
#pragma unroll
        for (int n = 0; n < 4; n++) {
            float xv = xs[(h * 4 + n) * 128 + d];
            a[n] += xv * wd;
            b[n] += xv * wb;
        }
    }
#pragma unroll
    for (int n = 0; n < 4; n++) {
        int gn = n0 + h * 4 + n;
        A[(size_t)gn * HD + c] = (ushort)f2bf(a[n]);
        Bm[(size_t)gn * HD + c] = (ushort)f2bf(b[n]);
    }
}

// ---------------- MFMA edge kernel (R6 structure) + phase-ablation instrumentation ----------------
// ABL: 0=full  1=no A/B gather  2=no weight-frag global loads  3=no MFMA  4=no aggregation
// REP: internal repeat count (diagnostic dispatches use 6 so they rank above full rows)
template<int DOUTB, int ABL, int REP>
__global__ __launch_bounds__(256, 2)
void edge_mfma_kernel(const ushort* __restrict__ Af, const ushort* __restrict__ Bf,
                      const ushort* __restrict__ W1T, const float* __restrict__ b1,
                      const ushort* __restrict__ W2T, const float* __restrict__ b2,
                      const int* __restrict__ ssrc, const int* __restrict__ nof,
                      float* __restrict__ out) {
    __shared__ __align__(16) ushort HH1[TILE * 136];   // h1 [e][k]; later m [c][e] bf16
    __shared__ __align__(16) ushort HH2[TILE * 136];   // h2 [e][c]
    __shared__ __align__(16) ushort ALDS[32 * 136];    // staged A rows
    __shared__ __align__(16) int s_node[TILE];
    __shared__ int s_src[TILE];

    const int t = threadIdx.x;
    const int lane = t & 63;
    const int w = t >> 6;
    const int lr = lane & 15;
    const int lg = lane >> 4;
    const int wr = w >> 1;      // L2 c-block
    const int wc = w & 1;       // L2 e-block

    const int ts = blockIdx.x * TILE;

    float bias2[4][4];
#pragma unroll
    for (int m = 0; m < 4; m++)
#pragma unroll
        for (int r = 0; r < 4; r++)
            bias2[m][r] = b1[wr * 64 + m * 16 + lg * 4 + r];

    constexpr int CT3 = DOUTB / 16;   // 8 or 1
    float bias3[CT3];
#pragma unroll
    for (int ct = 0; ct < CT3; ct++) bias3[ct] = b2[ct * 16 + lr];

    int keep = 0;               // DCE anchor for ablation variants (rule #17)
    s16x8 dumf;
    if constexpr (ABL == 2) {
#pragma unroll
        for (int j = 0; j < 8; j++) dumf[j] = f2bf(b1[0] * 0.01f * (float)(j + 1));
    }

    for (int rep = 0; rep < REP; ++rep) {
        __syncthreads();
        if (t < TILE) { s_node[t] = nof[ts + t]; s_src[t] = ssrc[ts + t]; }
        __syncthreads();
        const int nd0 = s_node[0];
        const int ndL = s_node[TILE - 1];

        // ---- h1 fill ----
        if constexpr (ABL == 1) {
            keep ^= s_src[t & 127];   // keep ssrc load alive
            for (int i = t; i < TILE * 16; i += 256) {
                const int e = i >> 4, cg = i & 15;
                s16x8 hv;
#pragma unroll
                for (int j = 0; j < 8; j++)
                    hv[j] = f2bf(0.03125f * (float)((e + cg * 8 + j + nd0) & 31));
                *(s16x8*)(HH1 + e * 136 + cg * 8) = hv;
            }
        } else if (ndL - nd0 < 32) {
            for (int i = t; i < (ndL - nd0 + 1) * 16; i += 256) {
                const int r = i >> 4, cg = i & 15;
                *(s16x8*)(ALDS + r * 136 + cg * 8) =
                    *(const s16x8*)(Af + (size_t)(nd0 + r) * HD + cg * 8);
            }
            __syncthreads();
            for (int i = t; i < TILE * 16; i += 256) {
                const int e = i >> 4, cg = i & 15;
                const s16x8 av = *(const s16x8*)(ALDS + (s_node[e] - nd0) * 136 + cg * 8);
                const s16x8 bv = *(const s16x8*)(Bf + (size_t)s_src[e] * HD + cg * 8);
                s16x8 hv;
#pragma unroll
                for (int j = 0; j < 8; j++)
                    hv[j] = f2bf(fmaxf(bf2f(av[j]) + bf2f(bv[j]), 0.f));
                *(s16x8*)(HH1 + e * 136 + cg * 8) = hv;
            }
        } else {
            for (int i = t; i < TILE * 16; i += 256) {
                const int e = i >> 4, cg = i & 15;
                const s16x8 av = *(const s16x8*)(Af + (size_t)s_node[e] * HD + cg * 8);
                const s16x8 bv = *(const s16x8*)(Bf + (size_t)s_src[e] * HD + cg * 8);
                s16x8 hv;
#pragma unroll
                for (int j = 0; j < 8; j++)
                    hv[j] = f2bf(fmaxf(bf2f(av[j]) + bf2f(bv[j]), 0.f));
                *(s16x8*)(HH1 + e * 136 + cg * 8) = hv;
            }
        }
        __syncthreads();

        // ---- layer 2: D[c][e] ----
        f32x4 acc[4][4];
#pragma unroll
        for (int m = 0; m < 4; m++)
#pragma unroll
            for (int n = 0; n < 4; n++) {
                f32x4 v; v[0] = bias2[m][0]; v[1] = bias2[m][1]; v[2] = bias2[m][2]; v[3] = bias2[m][3];
                acc[m][n] = v;
            }
#pragma unroll
        for (int ks = 0; ks < 4; ks++) {
            const int k0 = ks * 32 + lg * 8;
            s16x8 afr[4], bfr[4];
            if constexpr (ABL == 2) {
#pragma unroll
                for (int m = 0; m < 4; m++) afr[m] = dumf;
            } else {
#pragma unroll
                for (int m = 0; m < 4; m++)
                    afr[m] = *(const s16x8*)(W1T + (size_t)(wr * 64 + m * 16 + lr) * HD + k0);
            }
#pragma unroll
            for (int n = 0; n < 4; n++)
                bfr[n] = *(const s16x8*)(HH1 + (wc * 64 + n * 16 + lr) * 136 + k0);
            if constexpr (ABL == 3) {
#pragma unroll
                for (int m = 0; m < 4; m++) keep ^= (int)(short)afr[m][0];
#pragma unroll
                for (int n = 0; n < 4; n++) keep ^= (int)(short)bfr[n][0];
            } else {
#pragma unroll
                for (int m = 0; m < 4; m++)
#pragma unroll
                    for (int n = 0; n < 4; n++)
                        acc[m][n] = __builtin_amdgcn_mfma_f32_16x16x32_bf16(afr[m], bfr[n], acc[m][n], 0, 0, 0);
            }
        }
        // h2 = relu(acc) -> HH2[e][c]
#pragma unroll
        for (int m = 0; m < 4; m++)
#pragma unroll
            for (int n = 0; n < 4; n++) {
                const int e = wc * 64 + n * 16 + lr;
                const int c0 = wr * 64 + m * 16 + lg * 4;
                s16x4 hv;
                hv[0] = f2bf(fmaxf(acc[m][n][0], 0.f));
                hv[1] = f2bf(fmaxf(acc[m][n][1], 0.f));
                hv[2] = f2bf(fmaxf(acc[m][n][2], 0.f));
                hv[3] = f2bf(fmaxf(acc[m][n][3], 0.f));
                *(s16x4*)(HH2 + e * 136 + c0) = hv;
            }
        __syncthreads();

        // ---- layer 3 (swapped operands): D[e][c] ----
        f32x4 acc3[2][CT3];
#pragma unroll
        for (int e2 = 0; e2 < 2; e2++)
#pragma unroll
            for (int ct = 0; ct < CT3; ct++) {
                const float bb = bias3[ct];
                f32x4 v; v[0] = bb; v[1] = bb; v[2] = bb; v[3] = bb;
                acc3[e2][ct] = v;
            }
#pragma unroll
        for (int ks = 0; ks < 4; ks++) {
            const int k0 = ks * 32 + lg * 8;
            s16x8 h2f[2], wf[CT3];
#pragma unroll
            for (int e2 = 0; e2 < 2; e2++)
                h2f[e2] = *(const s16x8*)(HH2 + ((w * 2 + e2) * 16 + lr) * 136 + k0);
            if constexpr (ABL == 2) {
#pragma unroll
                for (int ct = 0; ct < CT3; ct++) wf[ct] = dumf;
            } else {
#pragma unroll
                for (int ct = 0; ct < CT3; ct++)
                    wf[ct] = *(const s16x8*)(W2T + (size_t)(ct * 16 + lr) * HD + k0);
            }
            if constexpr (ABL == 3) {
#pragma unroll
                for (int e2 = 0; e2 < 2; e2++) keep ^= (int)(short)h2f[e2][0];
#pragma unroll
                for (int ct = 0; ct < CT3; ct++) keep ^= (int)(short)wf[ct][0];
            } else {
#pragma unroll
                for (int e2 = 0; e2 < 2; e2++)
#pragma unroll
                    for (int ct = 0; ct < CT3; ct++)
                        acc3[e2][ct] = __builtin_amdgcn_mfma_f32_16x16x32_bf16(h2f[e2], wf[ct], acc3[e2][ct], 0, 0, 0);
            }
        }
        // write m bf16 -> HH1 as m[c][e]
#pragma unroll
        for (int e2 = 0; e2 < 2; e2++)
#pragma unroll
            for (int ct = 0; ct < CT3; ct++) {
                const int e0 = (w * 2 + e2) * 16 + lg * 4;
                const int c = ct * 16 + lr;
                s16x4 mv;
                mv[0] = f2bf(acc3[e2][ct][0]);
                mv[1] = f2bf(acc3[e2][ct][1]);
                mv[2] = f2bf(acc3[e2][ct][2]);
                mv[3] = f2bf(acc3[e2][ct][3]);
                *(s16x4*)(HH1 + c * 136 + e0) = mv;
            }
        __syncthreads();

        // ---- aggregation ----
        if constexpr (ABL == 4) {
            if (t < TILE) out[(size_t)ts + t] = bf2f(HH1[t * 136]);   // keep HH1 alive
        } else if constexpr (DOUTB == 128) {
            if (ndL - nd0 <= 15) {
                f32x4 agg[2];
                agg[0] = (f32x4)0.f; agg[1] = (f32x4)0.f;
#pragma unroll
                for (int ks = 0; ks < 4; ks++) {
                    const int4 na = *(const int4*)&s_node[ks * 32 + lg * 8];
                    const int4 nb = *(const int4*)&s_node[ks * 32 + lg * 8 + 4];
                    s16x8 sel;
                    sel[0] = (na.x - nd0 == lr) ? (short)0x3F80 : (short)0;
                    sel[1] = (na.y - nd0 == lr) ? (short)0x3F80 : (short)0;
                    sel[2] = (na.z - nd0 == lr) ? (short)0x3F80 : (short)0;
                    sel[3] = (na.w - nd0 == lr) ? (short)0x3F80 : (short)0;
                    sel[4] = (nb.x - nd0 == lr) ? (short)0x3F80 : (short)0;
                    sel[5] = (nb.y - nd0 == lr) ? (short)0x3F80 : (short)0;
                    sel[6] = (nb.z - nd0 == lr) ? (short)0x3F80 : (short)0;
                    sel[7] = (nb.w - nd0 == lr) ? (short)0x3F80 : (short)0;
#pragma unroll
                    for (int ci = 0; ci < 2; ci++) {
                        const s16x8 mf = *(const s16x8*)(HH1 + ((w * 2 + ci) * 16 + lr) * 136 + ks * 32 + lg * 8);
                        if constexpr (ABL == 3) { keep ^= (int)(short)mf[0]; keep ^= (int)(short)sel[0]; }
                        else agg[ci] = __builtin_amdgcn_mfma_f32_16x16x32_bf16(sel, mf, agg[ci], 0, 0, 0);
                    }
                }
#pragma unroll
                for (int ci = 0; ci < 2; ci++) {
                    const int c = (w * 2 + ci) * 16 + lr;
#pragma unroll
                    for (int r = 0; r < 4; r++) {
                        const int nd = nd0 + lg * 4 + r;
                        if (nd <= ndL) {
                            float* dp = out + (size_t)nd * 128 + c;
                            const float v = agg[ci][r];
                            if (nd > nd0 && nd < ndL) *dp = v;
                            else atomicAdd(dp, v);
                        }
                    }
                }
            } else {
                for (int idx = t; idx < TILE * 128; idx += 256) {
                    const int e = idx >> 7, c = idx & 127;
                    atomicAdd(out + (size_t)s_node[e] * 128 + c, bf2f(HH1[c * 136 + e]));
                }
            }
        } else {
            // DOUTB == 16
            const int nw0 = s_node[w * 32];
            const int nwL = s_node[w * 32 + 31];
            if (nwL - nw0 <= 15) {
                const int4 na = *(const int4*)&s_node[w * 32 + lg * 8];
                const int4 nb = *(const int4*)&s_node[w * 32 + lg * 8 + 4];
                s16x8 sel;
                sel[0] = (na.x - nw0 == lr) ? (short)0x3F80 : (short)0;
                sel[1] = (na.y - nw0 == lr) ? (short)0x3F80 : (short)0;
                sel[2] = (na.z - nw0 == lr) ? (short)0x3F80 : (short)0;
                sel[3] = (na.w - nw0 == lr) ? (short)0x3F80 : (short)0;
                sel[4] = (nb.x - nw0 == lr) ? (short)0x3F80 : (short)0;
                sel[5] = (nb.y - nw0 == lr) ? (short)0x3F80 : (short)0;
                sel[6] = (nb.z - nw0 == lr) ? (short)0x3F80 : (short)0;
                sel[7] = (nb.w - nw0 == lr) ? (short)0x3F80 : (short)0;
                const s16x8 mf = *(const s16x8*)(HH1 + lr * 136 + w * 32 + lg * 8);
                f32x4 agg = (f32x4)0.f;
                agg = __builtin_amdgcn_mfma_f32_16x16x32_bf16(sel, mf, agg, 0, 0, 0);
#pragma unroll
                for (int r = 0; r < 4; r++) {
                    const int nd = nw0 + lg * 4 + r;
                    if (nd <= nwL) {
                        float* dp = out + (size_t)nd * 16 + lr;
                        const float v = agg[r];
                        if (nd > nw0 && nd < nwL) *dp = v;
                        else atomicAdd(dp, v);
                    }
                }
            } else {
                for (int idx = lane; idx < 32 * 16; idx += 64) {
                    const int e = w * 32 + (idx >> 4), c = idx & 15;
                    atomicAdd(out + (size_t)s_node[e] * 16 + c, bf2f(HH1[c * 136 + e]));
                }
            }
        }
    }
    if constexpr (ABL != 0) asm volatile("" :: "v"(keep));
}

extern "C" void kernel_launch(void* const* d_in, const int* in_sizes, int n_in,
                              void* d_out, int out_size, void* d_ws, size_t ws_size,
                              hipStream_t stream) {
    const float* x = (const float*)d_in[0];
    const int* ei = (const int*)d_in[2];
    const int* src = ei;
    const int* dst = ei + NE;
    const float* W[4][3];
    const float* bs[4][3];
    for (int b = 0; b < 4; b++)
        for (int l = 0; l < 3; l++) {
            W[b][l]  = (const float*)d_in[4 + b * 6 + l * 2];
            bs[b][l] = (const float*)d_in[4 + b * 6 + l * 2 + 1];
        }

    float* x0   = (float*)d_ws;
    float* x1   = x0 + (size_t)NN * HD;
    ushort* A   = (ushort*)(x1 + (size_t)NN * HD);
    ushort* Bm  = A + (size_t)NN * HD;
    ushort* WT  = Bm + (size_t)NN * HD;       // 131072 ushort = 256 KB
    int* cnt    = (int*)(WT + 131072);
    int* rs     = cnt + NN;
    int* cur    = rs + NN + 1;
    int* ssrc   = cur + NN;
    int* nof    = ssrc + NE;
    float* out  = (float*)d_out;

    WPtrs wp;
    for (int b = 0; b < 4; b++) { wp.w[2 * b] = W[b][1]; wp.w[2 * b + 1] = W[b][2]; }
    hipMemsetAsync(cnt, 0, NN * sizeof(int), stream);
    hist_kernel<<<(NE + 255) / 256, 256, 0, stream>>>(dst, cnt, wp, WT);
    scan_kernel<<<1, 256, 0, stream>>>(cnt, rs, cur);
    scatter_kernel<<<(NE + 255) / 256, 256, 0, stream>>>(src, dst, cur, ssrc);
    nodeof_kernel<<<(NN + 255) / 256, 256, 0, stream>>>(rs, nof);

    const ushort* W1T[4];
    const ushort* W2T[4];
    for (int b = 0; b < 4; b++) { W1T[b] = WT + b * 16384; W2T[b] = WT + 65536 + b * 16384; }

    // ---- real pipeline (unchanged R6 semantics) ----
    nodeAB_kernel<4, 128><<<NN / 8, 256, 0, stream>>>(x, W[0][0], bs[0][0], A, Bm, x0);
    edge_mfma_kernel<128, 0, 1><<<NTILES, 256, 0, stream>>>(A, Bm, W1T[0], bs[0][1], W2T[0], bs[0][2], ssrc, nof, x0);
    nodeAB_kernel<128, 128><<<NN / 8, 256, 0, stream>>>(x0, W[1][0], bs[1][0], A, Bm, x1);
    edge_mfma_kernel<128, 0, 1><<<NTILES, 256, 0, stream>>>(A, Bm, W1T[1], bs[1][1], W2T[1], bs[1][2], ssrc, nof, x1);
    nodeAB_kernel<128, 128><<<NN / 8, 256, 0, stream>>>(x1, W[2][0], bs[2][0], A, Bm, x0);
    edge_mfma_kernel<128, 0, 1><<<NTILES, 256, 0, stream>>>(A, Bm, W1T[2], bs[2][1], W2T[2], bs[2][2], ssrc, nof, x0);
    nodeAB_kernel<128, 16><<<NN / 8, 256, 0, stream>>>(x0, W[3][0], bs[3][0], A, Bm, out);
    edge_mfma_kernel<16, 0, 1><<<NTILES, 256, 0, stream>>>(A, Bm, W1T[3], bs[3][1], W2T[3], bs[3][2], ssrc, nof, out);

    // ---- diagnostic ablation dispatches (write to x1 scratch; launched AFTER all real consumers) ----
    // _ord mapping: these are the 4 highest-_ord edge dispatches, in order ABL=1,2,3,4.
    edge_mfma_kernel<128, 1, 6><<<NTILES, 256, 0, stream>>>(A, Bm, W1T[1], bs[1][1], W2T[1], bs[1][2], ssrc, nof, x1);
    edge_mfma_kernel<128, 2, 6><<<NTILES, 256, 0, stream>>>(A, Bm, W1T[1], bs[1][1], W2T[1], bs[1][2], ssrc, nof, x1);
    edge_mfma_kernel<128, 3, 6><<<NTILES, 256, 0, stream>>>(A, Bm, W1T[1], bs[1][1], W2T[1], bs[1][2], ssrc, nof, x1);
    edge_mfma_kernel<128, 4, 6><<<NTILES, 256, 0, stream>>>(A, Bm, W1T[1], bs[1][1], W2T[1], bs[1][2], ssrc, nof, x1);
}

// Round 8
// 334.253 us; speedup vs baseline: 5.7181x; 5.7181x over previous
//
#include <hip/hip_runtime.h>
#include <hip/hip_bf16.h>

#define NN 10000
#define NE 320000
#define HD 128
#define TILE 128
#define NTILES (NE / TILE)   // 2500 exactly

typedef __attribute__((ext_vector_type(8))) short s16x8;
typedef __attribute__((ext_vector_type(4))) short s16x4;
typedef __attribute__((ext_vector_type(4))) float f32x4;

__device__ __forceinline__ short f2bf(float f) {
    union { float f; unsigned u; } v; v.f = f;
    unsigned r = v.u + 0x7FFFu + ((v.u >> 16) & 1u);   // RNE
    return (short)(r >> 16);
}
__device__ __forceinline__ float bf2f(short s) {
    union { unsigned u; float f; } v;
    v.u = ((unsigned)(unsigned short)s) << 16;
    return v.f;
}

// ---------------- CSR build (edges sorted by dst) + fused weight prep ----------------
struct WPtrs { const float* w[8]; };

__global__ void hist_kernel(const int* __restrict__ dst, int* __restrict__ cnt,
                            WPtrs p, ushort* __restrict__ wdst) {
    int e = blockIdx.x * blockDim.x + threadIdx.x;
    if (e < NE) atomicAdd(&cnt[dst[e]], 1);
    int tid = e;
    int m, idx;
    if (tid < 7 * 16384) { m = tid >> 14; idx = tid & 16383; }
    else if (tid < 7 * 16384 + 2048) { m = 7; idx = tid - 7 * 16384; }
    else return;
    int b = m >> 1, l = m & 1;
    int C = (m == 7) ? 16 : 128;
    int k = idx / C, c = idx % C;
    float v = p.w[m][k * C + c];
    wdst[l * 65536 + b * 16384 + c * 128 + k] = (ushort)f2bf(v);
}

__global__ void scan_kernel(const int* __restrict__ cnt, int* __restrict__ rs, int* __restrict__ cur) {
    __shared__ int part[256];
    int t = threadIdx.x;
    const int CH = (NN + 255) / 256;  // 40
    int base = t * CH;
    int s = 0;
    for (int i = 0; i < CH; i++) {
        int idx = base + i;
        if (idx < NN) s += cnt[idx];
    }
    part[t] = s;
    __syncthreads();
    for (int off = 1; off < 256; off <<= 1) {
        int v = (t >= off) ? part[t - off] : 0;
        __syncthreads();
        part[t] += v;
        __syncthreads();
    }
    int run = part[t] - s;
    for (int i = 0; i < CH; i++) {
        int idx = base + i;
        if (idx < NN) {
            rs[idx] = run;
            cur[idx] = run;
            run += cnt[idx];
        }
    }
    if (t == 255) rs[NN] = run;
}

__global__ void scatter_kernel(const int* __restrict__ src, const int* __restrict__ dst,
                               int* __restrict__ cur, int* __restrict__ ssrc) {
    int e = blockIdx.x * blockDim.x + threadIdx.x;
    if (e < NE) {
        int p = atomicAdd(&cur[dst[e]], 1);
        ssrc[p] = src[e];
    }
}

__global__ void nodeof_kernel(const int* __restrict__ rs, int* __restrict__ nof) {
    int n = blockIdx.x * blockDim.x + threadIdx.x;
    if (n < NN) {
        int b = rs[n], e = rs[n + 1];
        for (int s = b; s < e; s++) nof[s] = n;
    }
}

// ---------------- per-node layer-1 factorization -> bf16 A/B, fused zero-fill ----------------
template<int D, int ZD>
__global__ __launch_bounds__(256)
void nodeAB_kernel(const float* __restrict__ x, const float* __restrict__ W0,
                   const float* __restrict__ b0, ushort* __restrict__ A,
                   ushort* __restrict__ Bm, float* __restrict__ zbuf) {
    __shared__ float xs[8 * 128];
    int t = threadIdx.x;
    int n0 = blockIdx.x * 8;
    for (int i = t; i < 8 * D; i += 256) {
        int n = i / D, d = i % D;
        xs[n * 128 + d] = x[(size_t)(n0 + n) * D + d];
    }
    for (int i = t; i < 8 * ZD; i += 256) zbuf[(size_t)n0 * ZD + i] = 0.f;
    __syncthreads();
    int c = t & 127;
    int h = t >> 7;
    float a[4], b[4];
    float bias = b0[c];
#pragma unroll
    for (int n = 0; n < 4; n++) { a[n] = bias; b[n] = 0.f; }
    for (int d = 0; d < D; d++) {
        float wt = W0[d * HD + c];
        float wb = W0[(D + d) * HD + c];
        float wd = wt - wb;
#pragma unroll
        for (int n = 0; n < 4; n++) {
            float xv = xs[(h * 4 + n) * 128 + d];
            a[n] += xv * wd;
            b[n] += xv * wb;
        }
    }
#pragma unroll
    for (int n = 0; n < 4; n++) {
        int gn = n0 + h * 4 + n;
        A[(size_t)gn * HD + c] = (ushort)f2bf(a[n]);
        Bm[(size_t)gn * HD + c] = (ushort)f2bf(b[n]);
    }
}

// ---------------- persistent MFMA edge kernel: weights in VGPR, c-sliced per wave ----------------
// Wave w owns channel slice c in [w*32, (w+1)*32) for L2 (and for L3/agg when DOUTB=128).
// L2:  h2[c][e] = relu(Σ_k W1T[c][k] h1[e][k])     acc[2 m-tiles][8 e-tiles]
// L3:  m[e][c]  = Σ_k h2frag[e][k] W2T[c][k]       acc3[8 e-tiles][2 c-tiles]  (swapped operands)
// AGG: out[slot][c] = Σ_e sel[slot][e] m[e][c]     (sel one-hot from s_node)
// C/D frag: col = lane&15, row = (lane>>4)*4 + reg   [m89/m91 verified]
template<int DOUTB>
__global__ __launch_bounds__(256, 2)
void edge_mfma_kernel(const ushort* __restrict__ Af, const ushort* __restrict__ Bf,
                      const ushort* __restrict__ W1T, const float* __restrict__ b1,
                      const ushort* __restrict__ W2T, const float* __restrict__ b2,
                      const int* __restrict__ ssrc, const int* __restrict__ nof,
                      float* __restrict__ out) {
    __shared__ __align__(16) ushort HH1[TILE * 136];   // h1 [e][k]; later m [c][e] bf16
    __shared__ __align__(16) ushort HH2[TILE * 136];   // h2 [e][c]
    __shared__ __align__(16) ushort ALDS[32 * 136];    // staged A rows
    __shared__ __align__(16) int s_node[TILE];
    __shared__ int s_src[TILE];

    const int t = threadIdx.x;
    const int lane = t & 63;
    const int w = t >> 6;
    const int lr = lane & 15;
    const int lg = lane >> 4;

    // ---- persistent weight fragments (loaded ONCE per block; ~5 tiles amortize) ----
    s16x8 w1f[2][4];   // c-rows w*32 + m*16 + lr
#pragma unroll
    for (int m = 0; m < 2; m++)
#pragma unroll
        for (int ks = 0; ks < 4; ks++)
            w1f[m][ks] = *(const s16x8*)(W1T + (size_t)(w * 32 + m * 16 + lr) * HD + ks * 32 + lg * 8);

    constexpr int CT3 = (DOUTB == 128) ? 2 : 1;
    s16x8 w2f[CT3][4];
#pragma unroll
    for (int ct = 0; ct < CT3; ct++) {
        const int row = (DOUTB == 128) ? ((w * 2 + ct) * 16 + lr) : lr;
#pragma unroll
        for (int ks = 0; ks < 4; ks++)
            w2f[ct][ks] = *(const s16x8*)(W2T + (size_t)row * HD + ks * 32 + lg * 8);
    }

    float bias2[2][4];
#pragma unroll
    for (int m = 0; m < 2; m++)
#pragma unroll
        for (int r = 0; r < 4; r++)
            bias2[m][r] = b1[w * 32 + m * 16 + lg * 4 + r];
    float bias3[CT3];
#pragma unroll
    for (int ct = 0; ct < CT3; ct++)
        bias3[ct] = (DOUTB == 128) ? b2[(w * 2 + ct) * 16 + lr] : b2[lr];

    for (int tile = blockIdx.x; tile < NTILES; tile += gridDim.x) {
        const int ts = tile * TILE;
        __syncthreads();   // prev iteration fully consumed
        if (t < TILE) { s_node[t] = nof[ts + t]; s_src[t] = ssrc[ts + t]; }
        __syncthreads();
        const int nd0 = s_node[0];
        const int ndL = s_node[TILE - 1];

        // ---- h1 fill: HH1[e][k] = bf16(relu(A[dst][k] + B[src][k])), row-coalesced ----
        if (ndL - nd0 < 32) {
            for (int i = t; i < (ndL - nd0 + 1) * 16; i += 256) {
                const int r = i >> 4, cg = i & 15;
                *(s16x8*)(ALDS + r * 136 + cg * 8) =
                    *(const s16x8*)(Af + (size_t)(nd0 + r) * HD + cg * 8);
            }
            __syncthreads();
            for (int i = t; i < TILE * 16; i += 256) {
                const int e = i >> 4, cg = i & 15;
                const s16x8 av = *(const s16x8*)(ALDS + (s_node[e] - nd0) * 136 + cg * 8);
                const s16x8 bv = *(const s16x8*)(Bf + (size_t)s_src[e] * HD + cg * 8);
                s16x8 hv;
#pragma unroll
                for (int j = 0; j < 8; j++)
                    hv[j] = f2bf(fmaxf(bf2f(av[j]) + bf2f(bv[j]), 0.f));
                *(s16x8*)(HH1 + e * 136 + cg * 8) = hv;
            }
        } else {
            for (int i = t; i < TILE * 16; i += 256) {
                const int e = i >> 4, cg = i & 15;
                const s16x8 av = *(const s16x8*)(Af + (size_t)s_node[e] * HD + cg * 8);
                const s16x8 bv = *(const s16x8*)(Bf + (size_t)s_src[e] * HD + cg * 8);
                s16x8 hv;
#pragma unroll
                for (int j = 0; j < 8; j++)
                    hv[j] = f2bf(fmaxf(bf2f(av[j]) + bf2f(bv[j]), 0.f));
                *(s16x8*)(HH1 + e * 136 + cg * 8) = hv;
            }
        }
        __syncthreads();

        // ---- layer 2: D[c][e], wave's c-slice x ALL 128 edges ----
        f32x4 acc[2][8];
#pragma unroll
        for (int m = 0; m < 2; m++)
#pragma unroll
            for (int n = 0; n < 8; n++) {
                f32x4 v; v[0] = bias2[m][0]; v[1] = bias2[m][1]; v[2] = bias2[m][2]; v[3] = bias2[m][3];
                acc[m][n] = v;
            }
#pragma unroll
        for (int ks = 0; ks < 4; ks++) {
            const int k0 = ks * 32 + lg * 8;
            s16x8 bfr[8];
#pragma unroll
            for (int n = 0; n < 8; n++)
                bfr[n] = *(const s16x8*)(HH1 + (n * 16 + lr) * 136 + k0);
#pragma unroll
            for (int m = 0; m < 2; m++)
#pragma unroll
                for (int n = 0; n < 8; n++)
                    acc[m][n] = __builtin_amdgcn_mfma_f32_16x16x32_bf16(w1f[m][ks], bfr[n], acc[m][n], 0, 0, 0);
        }
        // h2 = relu(acc) -> HH2[e][c] (separate buffer, no barrier first)
#pragma unroll
        for (int m = 0; m < 2; m++)
#pragma unroll
            for (int n = 0; n < 8; n++) {
                const int e = n * 16 + lr;
                const int c0 = w * 32 + m * 16 + lg * 4;
                s16x4 hv;
                hv[0] = f2bf(fmaxf(acc[m][n][0], 0.f));
                hv[1] = f2bf(fmaxf(acc[m][n][1], 0.f));
                hv[2] = f2bf(fmaxf(acc[m][n][2], 0.f));
                hv[3] = f2bf(fmaxf(acc[m][n][3], 0.f));
                *(s16x4*)(HH2 + e * 136 + c0) = hv;
            }
        __syncthreads();   // h2 visible; all HH1 reads retired -> HH1 free for m

        // ---- layer 3 (swapped operands): D[e][c] ----
        if constexpr (DOUTB == 128) {
            f32x4 acc3[8][2];
#pragma unroll
            for (int n = 0; n < 8; n++)
#pragma unroll
                for (int ct = 0; ct < 2; ct++) {
                    const float bb = bias3[ct];
                    f32x4 v; v[0] = bb; v[1] = bb; v[2] = bb; v[3] = bb;
                    acc3[n][ct] = v;
                }
#pragma unroll
            for (int ks = 0; ks < 4; ks++) {
                const int k0 = ks * 32 + lg * 8;
                s16x8 h2f[8];
#pragma unroll
                for (int n = 0; n < 8; n++)
                    h2f[n] = *(const s16x8*)(HH2 + (n * 16 + lr) * 136 + k0);
#pragma unroll
                for (int n = 0; n < 8; n++)
#pragma unroll
                    for (int ct = 0; ct < 2; ct++)
                        acc3[n][ct] = __builtin_amdgcn_mfma_f32_16x16x32_bf16(h2f[n], w2f[ct][ks], acc3[n][ct], 0, 0, 0);
            }
            // m bf16 -> HH1 as m[c][e]; this wave's c-cols (w*2+ct)*16+lr, all e
#pragma unroll
            for (int n = 0; n < 8; n++)
#pragma unroll
                for (int ct = 0; ct < 2; ct++) {
                    const int e0 = n * 16 + lg * 4;
                    const int c = (w * 2 + ct) * 16 + lr;
                    s16x4 mv;
                    mv[0] = f2bf(acc3[n][ct][0]);
                    mv[1] = f2bf(acc3[n][ct][1]);
                    mv[2] = f2bf(acc3[n][ct][2]);
                    mv[3] = f2bf(acc3[n][ct][3]);
                    *(s16x4*)(HH1 + c * 136 + e0) = mv;
                }
        } else {
            // DOUTB == 16: single c-tile; waves split edges (e-tiles {2w, 2w+1})
            f32x4 acc3[2];
#pragma unroll
            for (int e2 = 0; e2 < 2; e2++) {
                const float bb = bias3[0];
                f32x4 v; v[0] = bb; v[1] = bb; v[2] = bb; v[3] = bb;
                acc3[e2] = v;
            }
#pragma unroll
            for (int ks = 0; ks < 4; ks++) {
                const int k0 = ks * 32 + lg * 8;
#pragma unroll
                for (int e2 = 0; e2 < 2; e2++) {
                    const s16x8 h2f = *(const s16x8*)(HH2 + ((w * 2 + e2) * 16 + lr) * 136 + k0);
                    acc3[e2] = __builtin_amdgcn_mfma_f32_16x16x32_bf16(h2f, w2f[0][ks], acc3[e2], 0, 0, 0);
                }
            }
#pragma unroll
            for (int e2 = 0; e2 < 2; e2++) {
                const int e0 = (w * 2 + e2) * 16 + lg * 4;
                const int c = lr;
                s16x4 mv;
                mv[0] = f2bf(acc3[e2][0]);
                mv[1] = f2bf(acc3[e2][1]);
                mv[2] = f2bf(acc3[e2][2]);
                mv[3] = f2bf(acc3[e2][3]);
                *(s16x4*)(HH1 + c * 136 + e0) = mv;
            }
        }
        __syncthreads();   // m visible

        // ---- aggregation via MFMA: out[slot][c] = Σ_e sel[slot][e] m[e][c] ----
        if constexpr (DOUTB == 128) {
            if (ndL - nd0 <= 15) {
                f32x4 agg[2];
                agg[0] = (f32x4)0.f; agg[1] = (f32x4)0.f;
#pragma unroll
                for (int ks = 0; ks < 4; ks++) {
                    const int4 na = *(const int4*)&s_node[ks * 32 + lg * 8];
                    const int4 nb = *(const int4*)&s_node[ks * 32 + lg * 8 + 4];
                    s16x8 sel;
                    sel[0] = (na.x - nd0 == lr) ? (short)0x3F80 : (short)0;
                    sel[1] = (na.y - nd0 == lr) ? (short)0x3F80 : (short)0;
                    sel[2] = (na.z - nd0 == lr) ? (short)0x3F80 : (short)0;
                    sel[3] = (na.w - nd0 == lr) ? (short)0x3F80 : (short)0;
                    sel[4] = (nb.x - nd0 == lr) ? (short)0x3F80 : (short)0;
                    sel[5] = (nb.y - nd0 == lr) ? (short)0x3F80 : (short)0;
                    sel[6] = (nb.z - nd0 == lr) ? (short)0x3F80 : (short)0;
                    sel[7] = (nb.w - nd0 == lr) ? (short)0x3F80 : (short)0;
#pragma unroll
                    for (int ci = 0; ci < 2; ci++) {
                        const s16x8 mf = *(const s16x8*)(HH1 + ((w * 2 + ci) * 16 + lr) * 136 + ks * 32 + lg * 8);
                        agg[ci] = __builtin_amdgcn_mfma_f32_16x16x32_bf16(sel, mf, agg[ci], 0, 0, 0);
                    }
                }
#pragma unroll
                for (int ci = 0; ci < 2; ci++) {
                    const int c = (w * 2 + ci) * 16 + lr;
#pragma unroll
                    for (int r = 0; r < 4; r++) {
                        const int nd = nd0 + lg * 4 + r;
                        if (nd <= ndL) {
                            float* dp = out + (size_t)nd * 128 + c;
                            const float v = agg[ci][r];
                            if (nd > nd0 && nd < ndL) *dp = v;
                            else atomicAdd(dp, v);
                        }
                    }
                }
            } else {
                for (int idx = t; idx < TILE * 128; idx += 256) {
                    const int e = idx >> 7, c = idx & 127;
                    atomicAdd(out + (size_t)s_node[e] * 128 + c, bf2f(HH1[c * 136 + e]));
                }
            }
        } else {
            // DOUTB == 16: each wave aggregates its own 32-edge window
            const int nw0 = s_node[w * 32];
            const int nwL = s_node[w * 32 + 31];
            if (nwL - nw0 <= 15) {
                const int4 na = *(const int4*)&s_node[w * 32 + lg * 8];
                const int4 nb = *(const int4*)&s_node[w * 32 + lg * 8 + 4];
                s16x8 sel;
                sel[0] = (na.x - nw0 == lr) ? (short)0x3F80 : (short)0;
                sel[1] = (na.y - nw0 == lr) ? (short)0x3F80 : (short)0;
                sel[2] = (na.z - nw0 == lr) ? (short)0x3F80 : (short)0;
                sel[3] = (na.w - nw0 == lr) ? (short)0x3F80 : (short)0;
                sel[4] = (nb.x - nw0 == lr) ? (short)0x3F80 : (short)0;
                sel[5] = (nb.y - nw0 == lr) ? (short)0x3F80 : (short)0;
                sel[6] = (nb.z - nw0 == lr) ? (short)0x3F80 : (short)0;
                sel[7] = (nb.w - nw0 == lr) ? (short)0x3F80 : (short)0;
                const s16x8 mf = *(const s16x8*)(HH1 + lr * 136 + w * 32 + lg * 8);
                f32x4 agg = (f32x4)0.f;
                agg = __builtin_amdgcn_mfma_f32_16x16x32_bf16(sel, mf, agg, 0, 0, 0);
#pragma unroll
                for (int r = 0; r < 4; r++) {
                    const int nd = nw0 + lg * 4 + r;
                    if (nd <= nwL) {
                        float* dp = out + (size_t)nd * 16 + lr;
                        const float v = agg[r];
                        if (nd > nw0 && nd < nwL) *dp = v;
                        else atomicAdd(dp, v);
                    }
                }
            } else {
                for (int idx = lane; idx < 32 * 16; idx += 64) {
                    const int e = w * 32 + (idx >> 4), c = idx & 15;
                    atomicAdd(out + (size_t)s_node[e] * 16 + c, bf2f(HH1[c * 136 + e]));
                }
            }
        }
    }
}

extern "C" void kernel_launch(void* const* d_in, const int* in_sizes, int n_in,
                              void* d_out, int out_size, void* d_ws, size_t ws_size,
                              hipStream_t stream) {
    const float* x = (const float*)d_in[0];
    const int* ei = (const int*)d_in[2];
    const int* src = ei;
    const int* dst = ei + NE;
    const float* W[4][3];
    const float* bs[4][3];
    for (int b = 0; b < 4; b++)
        for (int l = 0; l < 3; l++) {
            W[b][l]  = (const float*)d_in[4 + b * 6 + l * 2];
            bs[b][l] = (const float*)d_in[4 + b * 6 + l * 2 + 1];
        }

    float* x0   = (float*)d_ws;
    float* x1   = x0 + (size_t)NN * HD;
    ushort* A   = (ushort*)(x1 + (size_t)NN * HD);
    ushort* Bm  = A + (size_t)NN * HD;
    ushort* WT  = Bm + (size_t)NN * HD;       // 131072 ushort = 256 KB
    int* cnt    = (int*)(WT + 131072);
    int* rs     = cnt + NN;
    int* cur    = rs + NN + 1;
    int* ssrc   = cur + NN;
    int* nof    = ssrc + NE;
    float* out  = (float*)d_out;

    WPtrs wp;
    for (int b = 0; b < 4; b++) { wp.w[2 * b] = W[b][1]; wp.w[2 * b + 1] = W[b][2]; }
    hipMemsetAsync(cnt, 0, NN * sizeof(int), stream);
    hist_kernel<<<(NE + 255) / 256, 256, 0, stream>>>(dst, cnt, wp, WT);
    scan_kernel<<<1, 256, 0, stream>>>(cnt, rs, cur);
    scatter_kernel<<<(NE + 255) / 256, 256, 0, stream>>>(src, dst, cur, ssrc);
    nodeof_kernel<<<(NN + 255) / 256, 256, 0, stream>>>(rs, nof);

    const ushort* W1T[4];
    const ushort* W2T[4];
    for (int b = 0; b < 4; b++) { W1T[b] = WT + b * 16384; W2T[b] = WT + 65536 + b * 16384; }

    const int EG = 512;   // persistent, 2 blocks/CU, grid-stride over 2500 tiles

    // block 0 (nodeAB zeroes x0)
    nodeAB_kernel<4, 128><<<NN / 8, 256, 0, stream>>>(x, W[0][0], bs[0][0], A, Bm, x0);
    edge_mfma_kernel<128><<<EG, 256, 0, stream>>>(A, Bm, W1T[0], bs[0][1], W2T[0], bs[0][2], ssrc, nof, x0);
    // block 1 (zeroes x1)
    nodeAB_kernel<128, 128><<<NN / 8, 256, 0, stream>>>(x0, W[1][0], bs[1][0], A, Bm, x1);
    edge_mfma_kernel<128><<<EG, 256, 0, stream>>>(A, Bm, W1T[1], bs[1][1], W2T[1], bs[1][2], ssrc, nof, x1);
    // block 2 (zeroes x0)
    nodeAB_kernel<128, 128><<<NN / 8, 256, 0, stream>>>(x1, W[2][0], bs[2][0], A, Bm, x0);
    edge_mfma_kernel<128><<<EG, 256, 0, stream>>>(A, Bm, W1T[2], bs[2][1], W2T[2], bs[2][2], ssrc, nof, x0);
    // block 3 (zeroes out) -> d_out
    nodeAB_kernel<128, 16><<<NN / 8, 256, 0, stream>>>(x0, W[3][0], bs[3][0], A, Bm, out);
    edge_mfma_kernel<16><<<EG, 256, 0, stream>>>(A, Bm, W1T[3], bs[3][1], W2T[3], bs[3][2], ssrc, nof, out);
}